// Round 11
// baseline (551.001 us; speedup 1.0000x reference)
//
#include <hip/hip_runtime.h>
#include <hip/hip_fp16.h>

#define NUSERS 100000
#define NITEMS 200000
#define NNODES 300000
#define DIM 64
#define NEDGES 2000000

#define BSHIFT 5
#define NBUCK (NNODES >> BSHIFT)          // 9375 buckets of 32 nodes
#define NSUB 8                            // sub-cursors per bucket (XCD proxy)
#define SUBCAP 64                         // mean 26.7, sigma 5.2 -> +7 sigma
#define GB 8                              // buckets per 256-node group
#define NGROUP ((NNODES + 255) / 256)     // 1172
#define GCAP (GB * 320)                   // 2560 edata slots per group region

// Row layout (fp16): 64 halves = 128B = 16 int2. Lane l (0..15) owns int2 l.

// ---------------------------------------------------------------------------
// init: x0h = fp16(concat(user_emb, item_emb))
// ---------------------------------------------------------------------------
__global__ void init_h_kernel(const float4* __restrict__ user,
                              const float4* __restrict__ item,
                              int2* __restrict__ x0h) {
    int i = blockIdx.x * blockDim.x + threadIdx.x;
    const int n_user4 = NUSERS * (DIM / 4);
    const int n4 = NNODES * (DIM / 4);
    if (i < n4) {
        float4 v = (i < n_user4) ? user[i] : item[i - n_user4];
        __half2 h01 = __floats2half2_rn(v.x, v.y);
        __half2 h23 = __floats2half2_rn(v.z, v.w);
        int2 out;
        out.x = *reinterpret_cast<int*>(&h01);
        out.y = *reinterpret_cast<int*>(&h23);
        x0h[i] = out;
    }
}

// ---------------------------------------------------------------------------
// stage: append edge to (bucket, blockIdx&7) sub-region. Blocks with equal
// blockIdx&7 land on the same XCD (round-robin dispatch), so each 64B line
// of a sub-region is written through ONE XCD's L2 -> merged writeback.
// Packed: .x = dst | (src&255)<<19  (dst < 2^19), .y = val bits.
// ---------------------------------------------------------------------------
__global__ void stage_kernel(const int* __restrict__ src,
                             const int* __restrict__ dst,
                             const float* __restrict__ vals,
                             int* __restrict__ bcursor,
                             int2* __restrict__ staged) {
    int e = blockIdx.x * blockDim.x + threadIdx.x;
    int sub = blockIdx.x & (NSUB - 1);
    if (e < NEDGES) {
        int s = src[e];
        int cell = (s >> BSHIFT) * NSUB + sub;
        int p = atomicAdd(&bcursor[cell], 1);
        int2 ed;
        ed.x = dst[e] | ((s & 255) << 19);
        ed.y = __float_as_int(vals[e]);
        staged[(size_t)cell * SUBCAP + p] = ed;
    }
}

// ---------------------------------------------------------------------------
// finalize: one WG per 256-node group (= GB buckets x NSUB sub-regions).
// LDS node-histogram -> LDS scan -> per-node {begin,end} -> replay staged
// edges into node-sorted order within the group's fixed GCAP region.
// ---------------------------------------------------------------------------
__global__ void finalize_kernel(const int* __restrict__ bcursor,
                                const int2* __restrict__ staged,
                                int2* __restrict__ edata,
                                int2* __restrict__ range) {
    __shared__ int cnt[256];
    __shared__ int tmp[256];
    __shared__ int cur[256];
    __shared__ int bc[GB * NSUB];
    int g = blockIdx.x;
    int t = threadIdx.x;
    int b0 = g * GB;
    cnt[t] = 0;
    if (t < GB * NSUB) {
        int bidx = b0 + t / NSUB;
        bc[t] = (bidx < NBUCK) ? bcursor[b0 * NSUB + t] : 0;
    }
    __syncthreads();
    // per-node histogram (src low 8 bits == node index within group)
    for (int k = 0; k < GB * NSUB; ++k) {
        int c = bc[k];
        const int2* sp = staged + ((size_t)b0 * NSUB + k) * SUBCAP;
        for (int i = t; i < c; i += 256) {
            atomicAdd(&cnt[((unsigned)sp[i].x) >> 19], 1);
        }
    }
    __syncthreads();
    // exclusive scan of cnt
    int v = cnt[t];
    tmp[t] = v;
    __syncthreads();
    for (int off = 1; off < 256; off <<= 1) {
        int y = (t >= off) ? tmp[t - off] : 0;
        __syncthreads();
        tmp[t] += y;
        __syncthreads();
    }
    int excl = tmp[t] - v;
    int gbase = g * GCAP;
    int n = g * 256 + t;
    if (n < NNODES) {
        int2 r;
        r.x = gbase + excl;
        r.y = gbase + excl + v;
        range[n] = r;
    }
    cur[t] = excl;
    __syncthreads();
    // replay into node-sorted positions (writes confined to ~20KB window)
    for (int k = 0; k < GB * NSUB; ++k) {
        int c = bc[k];
        const int2* sp = staged + ((size_t)b0 * NSUB + k) * SUBCAP;
        for (int i = t; i < c; i += 256) {
            int2 ed = sp[i];
            int q = atomicAdd(&cur[((unsigned)ed.x) >> 19], 1);
            int2 out;
            out.x = ed.x & 0x7FFFF;
            out.y = ed.y;
            edata[(size_t)gbase + q] = out;
        }
    }
}

// ---------------------------------------------------------------------------
// mid gather: xnexth[n] = fp16( sum over edges of fp32(xh[dst]) * val )
// ---------------------------------------------------------------------------
__global__ void gather_mid_kernel(const int2* __restrict__ xh,
                                  const int2* __restrict__ range,
                                  const int2* __restrict__ edata,
                                  int2* __restrict__ xnexth) {
    int t = blockIdx.x * blockDim.x + threadIdx.x;
    int n = t >> 4;
    int lane = t & 15;
    if (n >= NNODES) return;
    int2 r = range[n];
    float s0 = 0.f, s1 = 0.f, s2 = 0.f, s3 = 0.f;
    for (int e = r.x; e < r.y; ++e) {
        int2 ed = edata[e];
        float v = __int_as_float(ed.y);
        int2 bits = xh[(size_t)ed.x * 16 + lane];
        __half2 h01 = *reinterpret_cast<__half2*>(&bits.x);
        __half2 h23 = *reinterpret_cast<__half2*>(&bits.y);
        float2 f01 = __half22float2(h01);
        float2 f23 = __half22float2(h23);
        s0 += f01.x * v; s1 += f01.y * v;
        s2 += f23.x * v; s3 += f23.y * v;
    }
    __half2 o01 = __floats2half2_rn(s0, s1);
    __half2 o23 = __floats2half2_rn(s2, s3);
    int2 out;
    out.x = *reinterpret_cast<int*>(&o01);
    out.y = *reinterpret_cast<int*>(&o23);
    xnexth[(size_t)n * 16 + lane] = out;
}

// ---------------------------------------------------------------------------
// final gather: acc[n] = 0.25*(x0h+x1h+x2h + sum fp32(x2h[dst])*val), fp32 out
// ---------------------------------------------------------------------------
__device__ __forceinline__ void unpack4(int2 bits, float& a, float& b,
                                        float& c, float& d) {
    __half2 h01 = *reinterpret_cast<__half2*>(&bits.x);
    __half2 h23 = *reinterpret_cast<__half2*>(&bits.y);
    float2 f01 = __half22float2(h01);
    float2 f23 = __half22float2(h23);
    a = f01.x; b = f01.y; c = f23.x; d = f23.y;
}

__global__ void gather_final_kernel(const int2* __restrict__ x2h,
                                    const int2* __restrict__ x0h,
                                    const int2* __restrict__ x1h,
                                    const int2* __restrict__ range,
                                    const int2* __restrict__ edata,
                                    float4* __restrict__ acc) {
    int t = blockIdx.x * blockDim.x + threadIdx.x;
    int n = t >> 4;
    int lane = t & 15;
    if (n >= NNODES) return;
    int2 r = range[n];
    float s0 = 0.f, s1 = 0.f, s2 = 0.f, s3 = 0.f;
    for (int e = r.x; e < r.y; ++e) {
        int2 ed = edata[e];
        float v = __int_as_float(ed.y);
        int2 bits = x2h[(size_t)ed.x * 16 + lane];
        float a, bb, c, d;
        unpack4(bits, a, bb, c, d);
        s0 += a * v; s1 += bb * v; s2 += c * v; s3 += d * v;
    }
    size_t o = (size_t)n * 16 + lane;
    float a0, b0, c0, d0, a1, b1, c1, d1, a2, b2, c2, d2;
    unpack4(x0h[o], a0, b0, c0, d0);
    unpack4(x1h[o], a1, b1, c1, d1);
    unpack4(x2h[o], a2, b2, c2, d2);
    float4 rr;
    rr.x = 0.25f * (a0 + a1 + a2 + s0);
    rr.y = 0.25f * (b0 + b1 + b2 + s1);
    rr.z = 0.25f * (c0 + c1 + c2 + s2);
    rr.w = 0.25f * (d0 + d1 + d2 + s3);
    acc[o] = rr;
}

extern "C" void kernel_launch(void* const* d_in, const int* in_sizes, int n_in,
                              void* d_out, int out_size, void* d_ws, size_t ws_size,
                              hipStream_t stream) {
    const float* user_emb = (const float*)d_in[0];
    const float* item_emb = (const float*)d_in[1];
    const float* edge_vals = (const float*)d_in[2];
    const int* edge_src = (const int*)d_in[3];
    const int* edge_dst = (const int*)d_in[4];
    float4* acc = (float4*)d_out;

    // ---- workspace layout (bytes) ----
    // staged (38.4MB) aliases x2h: staged is dead after finalize, before
    // gather-2 writes x2h. Total ws use ~142 MB.
    const size_t xh_bytes = (size_t)NNODES * DIM * 2;              // 38.4 MB
    char* ws = (char*)d_ws;
    int2* x0h     = (int2*)(ws);
    int2* x1h     = (int2*)(ws + xh_bytes);
    int2* x2h     = (int2*)(ws + 2 * xh_bytes);                    // = staged
    int2* staged  = x2h;
    char* p       = ws + 3 * xh_bytes;
    int2* range   = (int2*)p;   p += (size_t)NNODES * 8;           // 2.4 MB
    int* bcursor  = (int*)p;    p += (size_t)NBUCK * NSUB * 4;     // 300 KB
    int2* edata   = (int2*)p;                                      // 24 MB

    const int n4 = NNODES * (DIM / 4);
    dim3 blk(256);
    dim3 grid_nodes4((n4 + 255) / 256);
    dim3 grid_edges((NEDGES + 255) / 256);
    dim3 grid_groups(NGROUP);
    dim3 grid_gather((NNODES * 16 + 255) / 256);

    init_h_kernel<<<grid_nodes4, blk, 0, stream>>>(
        (const float4*)user_emb, (const float4*)item_emb, x0h);

    hipMemsetAsync(bcursor, 0, (size_t)NBUCK * NSUB * sizeof(int), stream);
    stage_kernel<<<grid_edges, blk, 0, stream>>>(edge_src, edge_dst, edge_vals,
                                                 bcursor, staged);
    finalize_kernel<<<grid_groups, blk, 0, stream>>>(bcursor, staged,
                                                     edata, range);

    gather_mid_kernel<<<grid_gather, blk, 0, stream>>>(x0h, range, edata, x1h);
    gather_mid_kernel<<<grid_gather, blk, 0, stream>>>(x1h, range, edata, x2h);
    gather_final_kernel<<<grid_gather, blk, 0, stream>>>(x2h, x0h, x1h,
                                                         range, edata, acc);
}